// Round 9
// baseline (82.215 us; speedup 1.0000x reference)
//
#include <hip/hip_runtime.h>

// VQ linear: out[b][o] = sum_k x[b][k] * dq[o][k]
// dq[o][k]: word = qweight[o][k/16]; nibble = (k/2)%8; idx = (word>>(4*nibble))&15;
//           dq[o][k] = lut[idx][k%2]
// Device dtypes (harness promotes reference f16 -> f32):
//   x (16,8192) f32, qweight (8192,512) i32, lut (16,2) f32, out (16,8192) f32.
// Values are exactly f16-representable -> lossless f32->f16, f16 MFMA, f32 accum.
//
// K-mapping: lane group g (= lane>>4) owns u16 indices [16g,16g+16) of its
// wave's 128 B qweight row-slice (two dwordx4 preloads); MFMA step j uses u16
// (16g+j) and x k-range [wave*512 + 128g + 8j, +8). A/B agree on the
// permutation; sum over k is order-invariant.
//
// Dequant LUT: two u32 tables (t0 = lut[byte&15] pair, t1 = lut[byte>>4] pair),
// each replicated 16x with 257-word stride (257 % 32 == 1 -> copy c shifts the
// bank of entry e to (e+c)%32). Lane l reads copy l&15: only 4 lanes share a
// copy -> ~2-way bank aliasing (free) instead of ~8-way on a single table.

typedef _Float16 half8 __attribute__((ext_vector_type(8)));
typedef float float4_t __attribute__((ext_vector_type(4)));
typedef unsigned int uint4_t __attribute__((ext_vector_type(4)));

#define O_FEAT 8192
#define I_FEAT 8192
#define WAVES 16
#define K_PER_WAVE (I_FEAT / WAVES)   // 512 halves = 64 u16 per row per wave
#define NJ (K_PER_WAVE / 32)          // 16 MFMA K-steps per wave
#define TILES 2                       // 32 outputs per block

// ---- pre-kernel: convert x f32 -> f16 into workspace (lossless) ----
__global__ void cvt_x_kernel(const float* __restrict__ x, _Float16* __restrict__ xf) {
    int i = (blockIdx.x * 256 + threadIdx.x) * 8;
    float4_t f0 = *(const float4_t*)(x + i);
    float4_t f1 = *(const float4_t*)(x + i + 4);
    half8 h = { (_Float16)f0[0], (_Float16)f0[1], (_Float16)f0[2], (_Float16)f0[3],
                (_Float16)f1[0], (_Float16)f1[1], (_Float16)f1[2], (_Float16)f1[3] };
    *(half8*)(xf + i) = h;
}

template <bool XF16>
__launch_bounds__(1024, 4)
__global__ void vq_gemm_kernel(const void* __restrict__ xsrc,
                               const unsigned char* __restrict__ qwb,  // qweight bytes
                               const float* __restrict__ lutf,         // lut (16,2) f32
                               float* __restrict__ out) {
    __shared__ unsigned int t0[16][257];   // byte -> packed 2xf16 of lut[byte&15]
    __shared__ unsigned int t1[16][257];   // byte -> packed 2xf16 of lut[byte>>4]
    __shared__ float4_t red[WAVES][TILES * 64];

    const int tid = threadIdx.x;

    // ---- build replicated tables (all 1024 threads; 4 copies each) ----
    {
        const int e = tid & 255;
        const int cb = tid >> 8;   // 0..3
        _Float16 a0 = (_Float16)lutf[(e & 15) * 2 + 0];
        _Float16 a1 = (_Float16)lutf[(e & 15) * 2 + 1];
        _Float16 h0 = (_Float16)lutf[(e >> 4) * 2 + 0];
        _Float16 h1 = (_Float16)lutf[(e >> 4) * 2 + 1];
        unsigned int lo = ((unsigned int)__builtin_bit_cast(unsigned short, a1) << 16)
                        |  (unsigned int)__builtin_bit_cast(unsigned short, a0);
        unsigned int hi = ((unsigned int)__builtin_bit_cast(unsigned short, h1) << 16)
                        |  (unsigned int)__builtin_bit_cast(unsigned short, h0);
#pragma unroll
        for (int i = 0; i < 4; ++i) {
            const int c = cb * 4 + i;   // 0..15
            t0[c][e] = lo;
            t1[c][e] = hi;
        }
    }

    const int wave = tid >> 6;
    const int lane = tid & 63;
    const int ln15 = lane & 15;   // A: batch row; B: output col within tile
    const int g    = lane >> 4;   // k-group 0..3

    const int obase = blockIdx.x * (TILES * 16);

    // qweight row = 2048 B; wave slice = 128 B; lane chunk = 32 B (contiguous)
    const unsigned char* qp0 = qwb + (size_t)(obase + ln15) * 2048 + wave * 128 + g * 32;
    const unsigned char* qp1 = qp0 + 16 * 2048;   // second 16-output tile

    uint4_t qa0 = *(const uint4_t*)(qp0);        // u16 idx 16g+0..7  (j=0..7)
    uint4_t qb0 = *(const uint4_t*)(qp0 + 16);   // u16 idx 16g+8..15 (j=8..15)
    uint4_t qa1 = *(const uint4_t*)(qp1);
    uint4_t qb1 = *(const uint4_t*)(qp1 + 16);

    const int xoff = ln15 * I_FEAT + wave * K_PER_WAVE + 128 * g;

    const unsigned int* tc0 = t0[ln15];   // per-lane copy (lane&15 == ln15)
    const unsigned int* tc1 = t1[ln15];

    __syncthreads();   // tables ready

    float4_t acc0 = {0.f, 0.f, 0.f, 0.f};
    float4_t acc1 = {0.f, 0.f, 0.f, 0.f};

#pragma unroll
    for (int j = 0; j < NJ; ++j) {
        half8 a;
        if constexpr (XF16) {
            a = *(const half8*)((const _Float16*)xsrc + xoff + 8 * j);
        } else {
            const float* xp = (const float*)xsrc + xoff + 8 * j;
            float4_t f0 = *(const float4_t*)xp;
            float4_t f1 = *(const float4_t*)(xp + 4);
            a = (half8){ (_Float16)f0[0], (_Float16)f0[1], (_Float16)f0[2], (_Float16)f0[3],
                         (_Float16)f1[0], (_Float16)f1[1], (_Float16)f1[2], (_Float16)f1[3] };
        }
        // u16 (16g + j): j<8 in qa*, j>=8 in qb*; odd j = high half of the u32.
        unsigned int w0 = (j < 8) ? qa0[(j >> 1) & 3] : qb0[(j >> 1) & 3];
        unsigned int w1 = (j < 8) ? qa1[(j >> 1) & 3] : qb1[(j >> 1) & 3];
        if (j & 1) { w0 >>= 16; w1 >>= 16; }
        const unsigned int b00 = w0 & 0xFF, b01 = (w0 >> 8) & 0xFF;
        const unsigned int b10 = w1 & 0xFF, b11 = (w1 >> 8) & 0xFF;
        uint4_t u0 = { tc0[b00], tc1[b00], tc0[b01], tc1[b01] };
        uint4_t u1 = { tc0[b10], tc1[b10], tc0[b11], tc1[b11] };
        half8 b0 = __builtin_bit_cast(half8, u0);
        half8 b1 = __builtin_bit_cast(half8, u1);
        acc0 = __builtin_amdgcn_mfma_f32_16x16x32_f16(a, b0, acc0, 0, 0, 0);
        acc1 = __builtin_amdgcn_mfma_f32_16x16x32_f16(a, b1, acc1, 0, 0, 0);
    }

    // Cross-wave K reduction via LDS (b128 writes, conflict-free).
    red[wave][lane] = acc0;
    red[wave][64 + lane] = acc1;
    __syncthreads();

    if (tid < 512) {
        const float* rf = (const float*)red;
        float s = 0.f;
#pragma unroll
        for (int w = 0; w < WAVES; ++w)
            s += rf[w * (TILES * 64 * 4) + tid];
        // tid -> (tile, lane, reg): D col n = lane&15, row m = (lane>>4)*4 + reg
        const int t2 = tid >> 8;
        const int l  = (tid >> 2) & 63;
        const int r  = tid & 3;
        const int m  = (l >> 4) * 4 + r;
        const int n  = l & 15;
        out[m * O_FEAT + obase + t2 * 16 + n] = s;
    }
}

extern "C" void kernel_launch(void* const* d_in, const int* in_sizes, int n_in,
                              void* d_out, int out_size, void* d_ws, size_t ws_size,
                              hipStream_t stream) {
    const float* x = (const float*)d_in[0];
    const unsigned char* qwb = (const unsigned char*)d_in[1];
    const float* lutf = (const float*)d_in[2];
    float* out = (float*)d_out;

    dim3 grid(O_FEAT / (TILES * 16));   // 256 blocks of 32 outputs (1 per CU)
    dim3 block(1024);                   // 16 waves: 16-way K split

    if (ws_size >= (size_t)(16 * I_FEAT * 2)) {
        cvt_x_kernel<<<dim3(16 * I_FEAT / (256 * 8)), dim3(256), 0, stream>>>(x, (_Float16*)d_ws);
        vq_gemm_kernel<true><<<grid, block, 0, stream>>>(d_ws, qwb, lutf, out);
    } else {
        vq_gemm_kernel<false><<<grid, block, 0, stream>>>(x, qwb, lutf, out);
    }
}